// Round 6
// baseline (414.314 us; speedup 1.0000x reference)
//
#include <hip/hip_runtime.h>
#include <stdint.h>

#define IN_F   2048
#define OUT_F  2048
#define NROWS  8192   // 4 * 2048
#define BK     64
#define BM     256    // block M tile
#define BN     128    // block N tile
#define NTILES (IN_F / BK)   // 32 K-tiles

typedef __bf16 bf16x8 __attribute__((ext_vector_type(8)));
typedef float  f32x16 __attribute__((ext_vector_type(16)));
typedef unsigned short ushort8v __attribute__((ext_vector_type(8)));

// ---------- helpers ----------

__device__ __forceinline__ unsigned short f2bf_rtne(float f) {
    unsigned int u = __float_as_uint(f);
    u += 0x7FFFu + ((u >> 16) & 1u);   // round-to-nearest-even on bf16 boundary
    return (unsigned short)(u >> 16);
}

__device__ __forceinline__ float softplusf(float v) {
    float a = fabsf(v);
    return fmaxf(v, 0.0f) + log1pf(__expf(-a));
}

// async global->LDS, 16B per lane; LDS dest is wave-uniform base + lane*16
__device__ __forceinline__ void gload_lds16(const void* g, void* l) {
    __builtin_amdgcn_global_load_lds(
        (const __attribute__((address_space(1))) unsigned int*)g,
        (__attribute__((address_space(3))) unsigned int*)l,
        16 /*bytes*/, 0 /*offset*/, 0 /*aux*/);
}

// ---------- prep: fused fp32 -> bf16 conversions into workspace ----------

__global__ __launch_bounds__(256)
void prep_kernel(const float* __restrict__ x, const float* __restrict__ mu,
                 const float* __restrict__ sg,
                 unsigned short* __restrict__ xb, unsigned short* __restrict__ kh,
                 unsigned short* __restrict__ mh) {
    const int b = blockIdx.x;
    const int t = threadIdx.x;
    if (b < 8192) {
        const size_t i = ((size_t)b * 256 + t) * 8;
        float4 v0 = *(const float4*)(x + i);
        float4 v1 = *(const float4*)(x + i + 4);
        ushort8v o;
        o[0] = f2bf_rtne(v0.x); o[1] = f2bf_rtne(v0.y);
        o[2] = f2bf_rtne(v0.z); o[3] = f2bf_rtne(v0.w);
        o[4] = f2bf_rtne(v1.x); o[5] = f2bf_rtne(v1.y);
        o[6] = f2bf_rtne(v1.z); o[7] = f2bf_rtne(v1.w);
        *(ushort8v*)(xb + i) = o;
    } else {
        const size_t i = ((size_t)(b - 8192) * 256 + t) * 8;
        float4 m0 = *(const float4*)(mu + i);
        float4 m1 = *(const float4*)(mu + i + 4);
        float4 s0 = *(const float4*)(sg + i);
        float4 s1 = *(const float4*)(sg + i + 4);
        ushort8v ko, mo;
        ko[0] = f2bf_rtne(m0.x * softplusf(s0.x));
        ko[1] = f2bf_rtne(m0.y * softplusf(s0.y));
        ko[2] = f2bf_rtne(m0.z * softplusf(s0.z));
        ko[3] = f2bf_rtne(m0.w * softplusf(s0.w));
        ko[4] = f2bf_rtne(m1.x * softplusf(s1.x));
        ko[5] = f2bf_rtne(m1.y * softplusf(s1.y));
        ko[6] = f2bf_rtne(m1.z * softplusf(s1.z));
        ko[7] = f2bf_rtne(m1.w * softplusf(s1.w));
        mo[0] = f2bf_rtne(m0.x); mo[1] = f2bf_rtne(m0.y);
        mo[2] = f2bf_rtne(m0.z); mo[3] = f2bf_rtne(m0.w);
        mo[4] = f2bf_rtne(m1.x); mo[5] = f2bf_rtne(m1.y);
        mo[6] = f2bf_rtne(m1.z); mo[7] = f2bf_rtne(m1.w);
        *(ushort8v*)(kh + i) = ko;
        *(ushort8v*)(mh + i) = mo;
    }
}

// ---------- fused double-GEMM, m201-style phase mechanics ----------
// Geometry = r1 (verified): BM=256 x BN=128, BK=64, 8 waves (4M x 2N),
// wave tile 64x64 dual-acc sharing A-frags; LDS [AL|AH|BL|BH] x 2 = 128 KB,
// chunk swizzle phys = c ^ ((row>>1)&3) on both DMA source and read side;
// 2 waves/SIMD.
// Schedule = m201 template mechanics: 2 phases per K-tile (low/high half):
//   { 12 ds_read_b128 hoisted  |  (PH0 only) stage ALL of tile t+1 (8 gloads) }
//   -> s_barrier -> lgkmcnt(0)+sched_barrier -> setprio(1) -> 16 MFMA
//   -> setprio(0) -> [PH1 only: vmcnt(0), ~2-phase lead] -> s_barrier.
// Loads for t+1 get the whole tile-t compute as landing time (r1's lead)
// while reads of the next half issue under the previous half's MFMA drain
// (the overlap r1 lacked). No counted mid-phase vmcnt (r2's marginal-lead
// stall source).

__global__ __launch_bounds__(512, 2)
void gemm_fused_kernel(const unsigned short* __restrict__ xb,  // [8192][2048] bf16
                       const unsigned short* __restrict__ kh,  // [2048][2048] bf16 keys
                       const unsigned short* __restrict__ mh,  // [2048][2048] bf16 mu
                       const float* __restrict__ gate,         // [2048]
                       float* __restrict__ out0,               // masked  [8192][2048]
                       float* __restrict__ out1,               // scores  [8192][2048]
                       float* __restrict__ out2)               // masked  [8192][2048]
{
    // [AL(2x8192) | AH(2x8192) | BL(2x8192: K@0,M@4096) | BH(2x8192)] ushorts
    __shared__ __align__(16) unsigned short lds[65536];   // 128 KB

    const int tid  = threadIdx.x;
    const int lane = tid & 63;
    const int wv   = tid >> 6;

    // XCD-aware bijective swizzle: 512 wgs, 8 XCDs, 64 consecutive wgs/XCD.
    const int swz = (blockIdx.x & 7) * 64 + (blockIdx.x >> 3);
    const int bm  = swz >> 4;    // 0..31 over M panels
    const int bo  = swz & 15;    // 0..15 over N panels

    const int wm = (wv >> 1) * 64;   // wave M offset: 0,64,128,192
    const int wn = (wv & 1) * 64;    // wave N offset: 0,64

    const int fm = lane & 31;
    const int hi = lane >> 5;

    // gate loads: retire under the prologue vmcnt(0)
    const float g0 = gate[bo * BN + wn + fm];
    const float g1 = gate[bo * BN + wn + 32 + fm];

    // ---- staging lane constants (region = 16 rows x 32 cols = 1KB) ----
    const int rr   = lane >> 2;
    const int scol = ((lane & 3) ^ ((lane >> 3) & 3)) * 8;
    const unsigned short* sA0 = xb + (size_t)(bm * BM + wv * 32 + rr) * IN_F + scol;
    const unsigned short* sA1 = sA0 + (size_t)16 * IN_F;
    const unsigned short* sK  = kh + (size_t)(bo * BN + wv * 16 + rr) * IN_F + scol;
    const unsigned short* sM  = mh + (size_t)(bo * BN + wv * 16 + rr) * IN_F + scol;

    // ---- fragment read constants ----
    const int swf   = (fm >> 1) & 3;
    const int aoff0 = (wm +      fm) * 32;
    const int aoff1 = (wm + 32 + fm) * 32;
    const int boff0 = (wn +      fm) * 32;
    const int boff1 = (wn + 32 + fm) * 32;
    const int eE    = ((0 + hi) ^ swf) * 8;   // kc even chunk within a half
    const int eO    = ((2 + hi) ^ swf) * 8;   // kc odd chunk

    f32x16 accS[2][2], accC[2][2];
#pragma unroll
    for (int i = 0; i < 2; ++i)
#pragma unroll
        for (int j = 0; j < 2; ++j)
#pragma unroll
            for (int r = 0; r < 16; ++r) { accS[i][j][r] = 0.f; accC[i][j][r] = 0.f; }

    auto STAGE_LOW = [&](int tt) {   // 4 gloads: A-low x2, K-low, M-low
        const int b2 = tt & 1;
        const int kt = tt * BK;
        unsigned short* ALb = &lds[b2 * 8192];
        unsigned short* BLb = &lds[32768 + b2 * 8192];
        gload_lds16(sA0 + kt, ALb + wv * 1024);
        gload_lds16(sA1 + kt, ALb + wv * 1024 + 512);
        gload_lds16(sK + kt, BLb + wv * 512);
        gload_lds16(sM + kt, BLb + 4096 + wv * 512);
    };
    auto STAGE_HIGH = [&](int tt) {  // 4 gloads: A-high x2, K-high, M-high
        const int b2 = tt & 1;
        const int kt = tt * BK + 32;
        unsigned short* AHb = &lds[16384 + b2 * 8192];
        unsigned short* BHb = &lds[49152 + b2 * 8192];
        gload_lds16(sA0 + kt, AHb + wv * 1024);
        gload_lds16(sA1 + kt, AHb + wv * 1024 + 512);
        gload_lds16(sK + kt, BHb + wv * 512);
        gload_lds16(sM + kt, BHb + 4096 + wv * 512);
    };

#define LDF(Abase, Bbase, e, a0, a1, k0, k1, m0, m1)                 \
    a0 = *(const bf16x8*)&(Abase)[aoff0 + (e)];                      \
    a1 = *(const bf16x8*)&(Abase)[aoff1 + (e)];                      \
    k0 = *(const bf16x8*)&(Bbase)[boff0 + (e)];                      \
    k1 = *(const bf16x8*)&(Bbase)[boff1 + (e)];                      \
    m0 = *(const bf16x8*)&(Bbase)[4096 + boff0 + (e)];               \
    m1 = *(const bf16x8*)&(Bbase)[4096 + boff1 + (e)];

#define MM8(a0, a1, k0, k1, m0, m1)                                                          \
    accS[0][0] = __builtin_amdgcn_mfma_f32_32x32x16_bf16(a0, k0, accS[0][0], 0, 0, 0);       \
    accS[0][1] = __builtin_amdgcn_mfma_f32_32x32x16_bf16(a0, k1, accS[0][1], 0, 0, 0);       \
    accS[1][0] = __builtin_amdgcn_mfma_f32_32x32x16_bf16(a1, k0, accS[1][0], 0, 0, 0);       \
    accS[1][1] = __builtin_amdgcn_mfma_f32_32x32x16_bf16(a1, k1, accS[1][1], 0, 0, 0);       \
    accC[0][0] = __builtin_amdgcn_mfma_f32_32x32x16_bf16(a0, m0, accC[0][0], 0, 0, 0);       \
    accC[0][1] = __builtin_amdgcn_mfma_f32_32x32x16_bf16(a0, m1, accC[0][1], 0, 0, 0);       \
    accC[1][0] = __builtin_amdgcn_mfma_f32_32x32x16_bf16(a1, m0, accC[1][0], 0, 0, 0);       \
    accC[1][1] = __builtin_amdgcn_mfma_f32_32x32x16_bf16(a1, m1, accC[1][1], 0, 0, 0);

#define SB0()   __builtin_amdgcn_sched_barrier(0)
#define LGKM0() asm volatile("s_waitcnt lgkmcnt(0)" ::: "memory")
#define VMW0()  asm volatile("s_waitcnt vmcnt(0)" ::: "memory")
#define BAR()   __builtin_amdgcn_s_barrier()

    // ---- prologue: stage tile 0 fully; full drain; barrier ----
    STAGE_LOW(0);
    STAGE_HIGH(0);
    VMW0();
    BAR(); SB0();

    bf16x8 A0, A1, K0, K1, M0, M1;   // even-kc frag set
    bf16x8 B0, B1, L0, L1, N0, N1;   // odd-kc frag set

    // ---- main loop: tiles 0..30, m201 phase mechanics ----
#pragma unroll 1
    for (int t = 0; t < NTILES - 1; ++t) {
        const int b = t & 1;
        const unsigned short* AL = &lds[b * 8192];
        const unsigned short* AH = &lds[16384 + b * 8192];
        const unsigned short* BL = &lds[32768 + b * 8192];
        const unsigned short* BH = &lds[49152 + b * 8192];

        // ---- PH0: low half (kc0, kc1) ----
        LDF(AL, BL, eE, A0, A1, K0, K1, M0, M1);   // 6 reads
        LDF(AL, BL, eO, B0, B1, L0, L1, N0, N1);   // 6 reads
        STAGE_LOW(t + 1);                          // 8 gloads for t+1,
        STAGE_HIGH(t + 1);                         //   ~2 phases of lead
        BAR();
        LGKM0(); SB0();
        __builtin_amdgcn_s_setprio(1);
        MM8(A0, A1, K0, K1, M0, M1);               // kc0
        MM8(B0, B1, L0, L1, N0, N1);               // kc1
        __builtin_amdgcn_s_setprio(0);
        BAR(); SB0();

        // ---- PH1: high half (kc2, kc3) ----
        LDF(AH, BH, eE, A0, A1, K0, K1, M0, M1);
        LDF(AH, BH, eO, B0, B1, L0, L1, N0, N1);
        BAR();
        LGKM0(); SB0();
        __builtin_amdgcn_s_setprio(1);
        MM8(A0, A1, K0, K1, M0, M1);               // kc2
        MM8(B0, B1, L0, L1, N0, N1);               // kc3
        __builtin_amdgcn_s_setprio(0);
        VMW0();                                    // t+1 landed (long lead)
        BAR(); SB0();
    }

    // ---- tail tile 31: no staging, no vm wait ----
    {
        const int b = (NTILES - 1) & 1;
        const unsigned short* AL = &lds[b * 8192];
        const unsigned short* AH = &lds[16384 + b * 8192];
        const unsigned short* BL = &lds[32768 + b * 8192];
        const unsigned short* BH = &lds[49152 + b * 8192];

        LDF(AL, BL, eE, A0, A1, K0, K1, M0, M1);
        LDF(AL, BL, eO, B0, B1, L0, L1, N0, N1);
        BAR();
        LGKM0(); SB0();
        __builtin_amdgcn_s_setprio(1);
        MM8(A0, A1, K0, K1, M0, M1);
        MM8(B0, B1, L0, L1, N0, N1);
        __builtin_amdgcn_s_setprio(0);
        BAR(); SB0();

        LDF(AH, BH, eE, A0, A1, K0, K1, M0, M1);
        LDF(AH, BH, eO, B0, B1, L0, L1, N0, N1);
        LGKM0(); SB0();
        __builtin_amdgcn_s_setprio(1);
        MM8(A0, A1, K0, K1, M0, M1);
        MM8(B0, B1, L0, L1, N0, N1);
        __builtin_amdgcn_s_setprio(0);
    }

    // ---- epilogue: 32x32 C/D layout: col=lane&31, row=(reg&3)+8*(reg>>2)+4*hi
    const float inv_sqrt_d = 0.022097086912079608f;  // 1/sqrt(2048)
    const size_t row_base = (size_t)bm * BM + wm;
    const int    col_base = bo * BN + wn;

#pragma unroll
    for (int i = 0; i < 2; ++i) {
#pragma unroll
        for (int j = 0; j < 2; ++j) {
            const float g   = j ? g1 : g0;
            const int   col = col_base + j * 32 + fm;
#pragma unroll
            for (int reg = 0; reg < 16; ++reg) {
                const int ro = (reg & 3) + 8 * (reg >> 2) + 4 * hi;
                const size_t row = row_base + i * 32 + ro;
                const size_t idx = row * OUT_F + col;
                const float s = accS[i][j][reg] * inv_sqrt_d;
                const float c = accC[i][j][reg];
                float w = s - g;
                w = w > 0.f ? w : 0.f;
                const float m = c * w;
                __builtin_nontemporal_store(m, &out0[idx]);
                __builtin_nontemporal_store(s, &out1[idx]);
                __builtin_nontemporal_store(m, &out2[idx]);
            }
        }
    }
#undef LDF
#undef MM8
#undef SB0
#undef LGKM0
#undef VMW0
#undef BAR
}

// ---------- launch ----------

extern "C" void kernel_launch(void* const* d_in, const int* in_sizes, int n_in,
                              void* d_out, int out_size, void* d_ws, size_t ws_size,
                              hipStream_t stream) {
    const float* x    = (const float*)d_in[0];   // [4,2048,2048]
    const float* mu   = (const float*)d_in[1];   // [2048,2048]
    const float* sg   = (const float*)d_in[2];   // [2048,2048]
    const float* gate = (const float*)d_in[3];   // [2048]

    float* out0 = (float*)d_out;                         // final_output
    float* out1 = out0 + (size_t)NROWS * OUT_F;          // scores
    float* out2 = out1 + (size_t)NROWS * OUT_F;          // masked_output

    // workspace layout (bf16): xb 33.55MB | kh 8.39MB | mh 8.39MB  (50.3MB)
    unsigned short* xb = (unsigned short*)d_ws;
    unsigned short* kh = xb + (size_t)NROWS * IN_F;
    unsigned short* mh = kh + (size_t)OUT_F * IN_F;

    prep_kernel<<<8192 + 2048, 256, 0, stream>>>(x, mu, sg, xb, kh, mh);

    dim3 grid(NROWS / BM * (OUT_F / BN));  // 32 * 16 = 512 blocks
    gemm_fused_kernel<<<grid, 512, 0, stream>>>(xb, kh, mh, gate, out0, out1, out2);
}

// Round 7
// 400.194 us; speedup vs baseline: 1.0353x; 1.0353x over previous
//
#include <hip/hip_runtime.h>
#include <stdint.h>

#define IN_F   2048
#define OUT_F  2048
#define NROWS  8192   // 4 * 2048
#define BK     64
#define BM     256    // block M tile
#define BN     128    // block N tile
#define NTILES (IN_F / BK)   // 32 K-tiles, 64 half-tiles

typedef __bf16 bf16x8 __attribute__((ext_vector_type(8)));
typedef float  f32x16 __attribute__((ext_vector_type(16)));
typedef unsigned short ushort8v __attribute__((ext_vector_type(8)));

// ---------- helpers ----------

__device__ __forceinline__ unsigned short f2bf_rtne(float f) {
    unsigned int u = __float_as_uint(f);
    u += 0x7FFFu + ((u >> 16) & 1u);   // round-to-nearest-even on bf16 boundary
    return (unsigned short)(u >> 16);
}

__device__ __forceinline__ float softplusf(float v) {
    float a = fabsf(v);
    return fmaxf(v, 0.0f) + log1pf(__expf(-a));
}

// async global->LDS, 16B per lane; LDS dest is wave-uniform base + lane*16
__device__ __forceinline__ void gload_lds16(const void* g, void* l) {
    __builtin_amdgcn_global_load_lds(
        (const __attribute__((address_space(1))) unsigned int*)g,
        (__attribute__((address_space(3))) unsigned int*)l,
        16 /*bytes*/, 0 /*offset*/, 0 /*aux*/);
}

// ---------- prep: fused fp32 -> bf16 conversions into workspace ----------

__global__ __launch_bounds__(256)
void prep_kernel(const float* __restrict__ x, const float* __restrict__ mu,
                 const float* __restrict__ sg,
                 unsigned short* __restrict__ xb, unsigned short* __restrict__ kh,
                 unsigned short* __restrict__ mh) {
    const int b = blockIdx.x;
    const int t = threadIdx.x;
    if (b < 8192) {
        const size_t i = ((size_t)b * 256 + t) * 8;
        float4 v0 = *(const float4*)(x + i);
        float4 v1 = *(const float4*)(x + i + 4);
        ushort8v o;
        o[0] = f2bf_rtne(v0.x); o[1] = f2bf_rtne(v0.y);
        o[2] = f2bf_rtne(v0.z); o[3] = f2bf_rtne(v0.w);
        o[4] = f2bf_rtne(v1.x); o[5] = f2bf_rtne(v1.y);
        o[6] = f2bf_rtne(v1.z); o[7] = f2bf_rtne(v1.w);
        *(ushort8v*)(xb + i) = o;
    } else {
        const size_t i = ((size_t)(b - 8192) * 256 + t) * 8;
        float4 m0 = *(const float4*)(mu + i);
        float4 m1 = *(const float4*)(mu + i + 4);
        float4 s0 = *(const float4*)(sg + i);
        float4 s1 = *(const float4*)(sg + i + 4);
        ushort8v ko, mo;
        ko[0] = f2bf_rtne(m0.x * softplusf(s0.x));
        ko[1] = f2bf_rtne(m0.y * softplusf(s0.y));
        ko[2] = f2bf_rtne(m0.z * softplusf(s0.z));
        ko[3] = f2bf_rtne(m0.w * softplusf(s0.w));
        ko[4] = f2bf_rtne(m1.x * softplusf(s1.x));
        ko[5] = f2bf_rtne(m1.y * softplusf(s1.y));
        ko[6] = f2bf_rtne(m1.z * softplusf(s1.z));
        ko[7] = f2bf_rtne(m1.w * softplusf(s1.w));
        mo[0] = f2bf_rtne(m0.x); mo[1] = f2bf_rtne(m0.y);
        mo[2] = f2bf_rtne(m0.z); mo[3] = f2bf_rtne(m0.w);
        mo[4] = f2bf_rtne(m1.x); mo[5] = f2bf_rtne(m1.y);
        mo[6] = f2bf_rtne(m1.z); mo[7] = f2bf_rtne(m1.w);
        *(ushort8v*)(kh + i) = ko;
        *(ushort8v*)(mh + i) = mo;
    }
}

// ---------- fused double-GEMM, ring-4 half-tile pipeline ----------
// Geometry = r4 (verified numerics): BM=256 x BN=128, 4 waves (2M x 2N),
// wave tile 128x64 dual-acc (16 f32x16 acc), 1 wave/SIMD.
// Half-tile = 32 K-cols: A 256x32 (16KB) + K 128x32 (8KB) + M 128x32 (8KB)
// = 32 KB. Ring of 4 half-buffers = 128 KB.
// Phase h (64 phases total):
//   STAGE(h+3 -> buf[(h+3)%4])            8 gloads  (2.5-phase lead)
//   read frags(h+1) from buf[(h+1)%4]    16 ds_read (FULL-phase lead)
//   sched_barrier
//   MFMA f(h) from regs (32 MFMA)         reads f(h+1) drain underneath
//   vmcnt(8)  => half h+2 landed (per-wave; counted, never 0 mid-loop)
//   s_barrier => h+2 globally visible; all reads of buf[(h-1)%4] done
// Invariants: stage lead 2.5 phases (~2600cy >> 900 HBM lat); read lead
// 1 phase (~1000cy >> 120 LDS lat) -- fixes r4's exposed read latency at
// 1 wave/SIMD. Chunk swizzle phys = c ^ ((row>>1)&3) both sides (r4).

__global__ __launch_bounds__(256, 1)
void gemm_fused_kernel(const unsigned short* __restrict__ xb,  // [8192][2048] bf16
                       const unsigned short* __restrict__ kh,  // [2048][2048] bf16 keys
                       const unsigned short* __restrict__ mh,  // [2048][2048] bf16 mu
                       const float* __restrict__ gate,         // [2048]
                       float* __restrict__ out0,               // masked  [8192][2048]
                       float* __restrict__ out1,               // scores  [8192][2048]
                       float* __restrict__ out2)               // masked  [8192][2048]
{
    // 4 half-buffers x 16384 ushorts: [A 8192 | K 4096 | M 4096]
    __shared__ __align__(16) unsigned short lds[65536];   // 128 KB

    const int tid  = threadIdx.x;
    const int lane = tid & 63;
    const int wv   = tid >> 6;       // 0..3

    // XCD-aware bijective swizzle: 512 wgs, 8 XCDs, 64 consecutive wgs/XCD.
    const int swz = (blockIdx.x & 7) * 64 + (blockIdx.x >> 3);
    const int bm  = swz >> 4;    // 0..31 over M panels
    const int bo  = swz & 15;    // 0..15 over N panels

    const int wm = (wv >> 1) * 128;  // wave M offset: 0,128
    const int wn = (wv & 1) * 64;    // wave N offset: 0,64

    const int fm = lane & 31;
    const int hi = lane >> 5;

    // gate loads first: oldest VMEM, retired by the prologue vmcnt(8)
    const float g0 = gate[bo * BN + wn + fm];
    const float g1 = gate[bo * BN + wn + 32 + fm];

    // ---- staging lane constants (region = 16 rows x 32 cols = 1KB) ----
    const int rr   = lane >> 2;
    const int scol = ((lane & 3) ^ ((lane >> 3) & 3)) * 8;
    const unsigned short* sA = xb + (size_t)(bm * BM + wv * 64 + rr) * IN_F + scol;
    const unsigned short* sK = kh + (size_t)(bo * BN + wv * 32 + rr) * IN_F + scol;
    const unsigned short* sM = mh + (size_t)(bo * BN + wv * 32 + rr) * IN_F + scol;

    // ---- fragment read constants ----
    const int swf = (fm >> 1) & 3;
    const int ao0 = (wm +      fm) * 32;
    const int ao1 = (wm +  32 + fm) * 32;
    const int ao2 = (wm +  64 + fm) * 32;
    const int ao3 = (wm +  96 + fm) * 32;
    const int no0 = (wn +      fm) * 32;
    const int no1 = (wn +  32 + fm) * 32;
    const int eE  = ((0 + hi) ^ swf) * 8;   // kc even chunk within a half
    const int eO  = ((2 + hi) ^ swf) * 8;   // kc odd chunk

    f32x16 accS[4][2], accC[4][2];
#pragma unroll
    for (int i = 0; i < 4; ++i)
#pragma unroll
        for (int j = 0; j < 2; ++j)
#pragma unroll
            for (int r = 0; r < 16; ++r) { accS[i][j][r] = 0.f; accC[i][j][r] = 0.f; }

    // stage half-tile at K-offset kt into ring buffer q (8 gloads)
#define STAGEH(kt, q) do {                                                       \
    unsigned short* Aq = &lds[(q) * 16384];                                      \
    unsigned short* Kq = Aq + 8192;                                              \
    unsigned short* Mq = Aq + 12288;                                             \
    gload_lds16(sA + (kt),                     Aq + (wv * 4 + 0) * 512);         \
    gload_lds16(sA + (kt) + (size_t)16 * IN_F, Aq + (wv * 4 + 1) * 512);         \
    gload_lds16(sA + (kt) + (size_t)32 * IN_F, Aq + (wv * 4 + 2) * 512);         \
    gload_lds16(sA + (kt) + (size_t)48 * IN_F, Aq + (wv * 4 + 3) * 512);         \
    gload_lds16(sK + (kt),                     Kq + (wv * 2 + 0) * 512);         \
    gload_lds16(sK + (kt) + (size_t)16 * IN_F, Kq + (wv * 2 + 1) * 512);         \
    gload_lds16(sM + (kt),                     Mq + (wv * 2 + 0) * 512);         \
    gload_lds16(sM + (kt) + (size_t)16 * IN_F, Mq + (wv * 2 + 1) * 512);         \
} while (0)

#define LDFRAG(Ab, Bb, e, a0, a1, a2, a3, k0, k1, m0, m1)            \
    a0 = *(const bf16x8*)&(Ab)[ao0 + (e)];                           \
    a1 = *(const bf16x8*)&(Ab)[ao1 + (e)];                           \
    a2 = *(const bf16x8*)&(Ab)[ao2 + (e)];                           \
    a3 = *(const bf16x8*)&(Ab)[ao3 + (e)];                           \
    k0 = *(const bf16x8*)&(Bb)[no0 + (e)];                           \
    k1 = *(const bf16x8*)&(Bb)[no1 + (e)];                           \
    m0 = *(const bf16x8*)&(Bb)[4096 + no0 + (e)];                    \
    m1 = *(const bf16x8*)&(Bb)[4096 + no1 + (e)];

    // load both kc-subsets of half-buffer q into a 16-frag set
#define LDSET(q, A0,A1,A2,A3,K0,K1,M0,M1, B0,B1,B2,B3,L0,L1,N0,N1) do {         \
    const unsigned short* Aq = &lds[(q) * 16384];                                \
    const unsigned short* Kq = Aq + 8192;                                        \
    LDFRAG(Aq, Kq, eE, A0, A1, A2, A3, K0, K1, M0, M1);                          \
    LDFRAG(Aq, Kq, eO, B0, B1, B2, B3, L0, L1, N0, N1);                          \
} while (0)

#define MM16(a0, a1, a2, a3, k0, k1, m0, m1)                                                 \
    __builtin_amdgcn_s_setprio(1);                                                           \
    accS[0][0] = __builtin_amdgcn_mfma_f32_32x32x16_bf16(a0, k0, accS[0][0], 0, 0, 0);       \
    accS[0][1] = __builtin_amdgcn_mfma_f32_32x32x16_bf16(a0, k1, accS[0][1], 0, 0, 0);       \
    accC[0][0] = __builtin_amdgcn_mfma_f32_32x32x16_bf16(a0, m0, accC[0][0], 0, 0, 0);       \
    accC[0][1] = __builtin_amdgcn_mfma_f32_32x32x16_bf16(a0, m1, accC[0][1], 0, 0, 0);       \
    accS[1][0] = __builtin_amdgcn_mfma_f32_32x32x16_bf16(a1, k0, accS[1][0], 0, 0, 0);       \
    accS[1][1] = __builtin_amdgcn_mfma_f32_32x32x16_bf16(a1, k1, accS[1][1], 0, 0, 0);       \
    accC[1][0] = __builtin_amdgcn_mfma_f32_32x32x16_bf16(a1, m0, accC[1][0], 0, 0, 0);       \
    accC[1][1] = __builtin_amdgcn_mfma_f32_32x32x16_bf16(a1, m1, accC[1][1], 0, 0, 0);       \
    accS[2][0] = __builtin_amdgcn_mfma_f32_32x32x16_bf16(a2, k0, accS[2][0], 0, 0, 0);       \
    accS[2][1] = __builtin_amdgcn_mfma_f32_32x32x16_bf16(a2, k1, accS[2][1], 0, 0, 0);       \
    accC[2][0] = __builtin_amdgcn_mfma_f32_32x32x16_bf16(a2, m0, accC[2][0], 0, 0, 0);       \
    accC[2][1] = __builtin_amdgcn_mfma_f32_32x32x16_bf16(a2, m1, accC[2][1], 0, 0, 0);       \
    accS[3][0] = __builtin_amdgcn_mfma_f32_32x32x16_bf16(a3, k0, accS[3][0], 0, 0, 0);       \
    accS[3][1] = __builtin_amdgcn_mfma_f32_32x32x16_bf16(a3, k1, accS[3][1], 0, 0, 0);       \
    accC[3][0] = __builtin_amdgcn_mfma_f32_32x32x16_bf16(a3, m0, accC[3][0], 0, 0, 0);       \
    accC[3][1] = __builtin_amdgcn_mfma_f32_32x32x16_bf16(a3, m1, accC[3][1], 0, 0, 0);       \
    __builtin_amdgcn_s_setprio(0);

    bf16x8 xa0, xa1, xa2, xa3, xk0, xk1, xm0, xm1;   // set X, even kc
    bf16x8 xb0, xb1, xb2, xb3, xl0, xl1, xn0, xn1;   // set X, odd  kc
    bf16x8 ya0, ya1, ya2, ya3, yk0, yk1, ym0, ym1;   // set Y, even kc
    bf16x8 yb0, yb1, yb2, yb3, yl0, yl1, yn0, yn1;   // set Y, odd  kc

#define LDX(q) LDSET(q, xa0,xa1,xa2,xa3,xk0,xk1,xm0,xm1, xb0,xb1,xb2,xb3,xl0,xl1,xn0,xn1)
#define LDY(q) LDSET(q, ya0,ya1,ya2,ya3,yk0,yk1,ym0,ym1, yb0,yb1,yb2,yb3,yl0,yl1,yn0,yn1)
#define MMX()  do { MM16(xa0,xa1,xa2,xa3,xk0,xk1,xm0,xm1); MM16(xb0,xb1,xb2,xb3,xl0,xl1,xn0,xn1); } while (0)
#define MMY()  do { MM16(ya0,ya1,ya2,ya3,yk0,yk1,ym0,ym1); MM16(yb0,yb1,yb2,yb3,yl0,yl1,yn0,yn1); } while (0)

#define SB0()   __builtin_amdgcn_sched_barrier(0)
#define VMW(n)  asm volatile("s_waitcnt vmcnt(" #n ")" ::: "memory")
#define BAR()   __builtin_amdgcn_s_barrier()

    // ---- prologue: stage halves 0,1,2; gates+halves0,1 landed; read f0 ----
    STAGEH(0,  0);
    STAGEH(32, 1);
    STAGEH(64, 2);
    VMW(8);                 // outstanding: half2 only (gates, h0, h1 retired)
    BAR(); SB0();
    LDX(0);                 // f0 frags
    SB0();

    // ---- main loop: u = 2 K-tiles = 4 phases; phases h = 4u .. 4u+3 ----
    // invariant at end of phase h: vmcnt(8)+barrier => half h+2 landed globally
#pragma unroll 1
    for (int u = 0; u < 15; ++u) {
        const int kb = u * 128;
        // phase 4u+0: stage half 4u+3 -> buf3, read f(4u+1) from buf1, MFMA f(4u)
        STAGEH(kb + 96, 3);
        LDY(1);
        SB0();
        MMX();
        VMW(8); BAR(); SB0();
        // phase 4u+1: stage half 4u+4 -> buf0, read f(4u+2) from buf2, MFMA f(4u+1)
        STAGEH(kb + 128, 0);
        LDX(2);
        SB0();
        MMY();
        VMW(8); BAR(); SB0();
        // phase 4u+2: stage half 4u+5 -> buf1, read f(4u+3) from buf3, MFMA f(4u+2)
        STAGEH(kb + 160, 1);
        LDY(3);
        SB0();
        MMX();
        VMW(8); BAR(); SB0();
        // phase 4u+3: stage half 4u+6 -> buf2, read f(4u+4) from buf0, MFMA f(4u+3)
        STAGEH(kb + 192, 2);
        LDX(0);
        SB0();
        MMY();
        VMW(8); BAR(); SB0();
    }

    // ---- tail: phases 60..63 (halves 60..63, K offsets 1920..2016) ----
    // h=60: last stage (half 63 -> buf3)
    STAGEH(2016, 3);
    LDY(1);                 // f61
    SB0();
    MMX();                  // f60
    VMW(8); BAR(); SB0();   // => half 62 landed
    // h=61
    LDX(2);                 // f62
    SB0();
    MMY();                  // f61
    VMW(0); BAR(); SB0();   // => half 63 landed
    // h=62
    LDY(3);                 // f63
    SB0();
    MMX();                  // f62
    SB0();
    // h=63
    MMY();                  // f63

    // ---- epilogue: 32x32 C/D layout: col=lane&31, row=(reg&3)+8*(reg>>2)+4*hi
    const float inv_sqrt_d = 0.022097086912079608f;  // 1/sqrt(2048)
    const size_t row_base = (size_t)bm * BM + wm;
    const int    col_base = bo * BN + wn;

#pragma unroll
    for (int i = 0; i < 4; ++i) {
#pragma unroll
        for (int j = 0; j < 2; ++j) {
            const float g   = j ? g1 : g0;
            const int   col = col_base + j * 32 + fm;
#pragma unroll
            for (int reg = 0; reg < 16; ++reg) {
                const int ro = (reg & 3) + 8 * (reg >> 2) + 4 * hi;
                const size_t row = row_base + i * 32 + ro;
                const size_t idx = row * OUT_F + col;
                const float s = accS[i][j][reg] * inv_sqrt_d;
                const float c = accC[i][j][reg];
                float w = s - g;
                w = w > 0.f ? w : 0.f;
                const float m = c * w;
                __builtin_nontemporal_store(m, &out0[idx]);
                __builtin_nontemporal_store(s, &out1[idx]);
                __builtin_nontemporal_store(m, &out2[idx]);
            }
        }
    }
#undef STAGEH
#undef LDFRAG
#undef LDSET
#undef LDX
#undef LDY
#undef MMX
#undef MMY
#undef MM16
#undef SB0
#undef VMW
#undef BAR
}

// ---------- launch ----------

extern "C" void kernel_launch(void* const* d_in, const int* in_sizes, int n_in,
                              void* d_out, int out_size, void* d_ws, size_t ws_size,
                              hipStream_t stream) {
    const float* x    = (const float*)d_in[0];   // [4,2048,2048]
    const float* mu   = (const float*)d_in[1];   // [2048,2048]
    const float* sg   = (const float*)d_in[2];   // [2048,2048]
    const float* gate = (const float*)d_in[3];   // [2048]

    float* out0 = (float*)d_out;                         // final_output
    float* out1 = out0 + (size_t)NROWS * OUT_F;          // scores
    float* out2 = out1 + (size_t)NROWS * OUT_F;          // masked_output

    // workspace layout (bf16): xb 33.55MB | kh 8.39MB | mh 8.39MB  (50.3MB)
    unsigned short* xb = (unsigned short*)d_ws;
    unsigned short* kh = xb + (size_t)NROWS * IN_F;
    unsigned short* mh = kh + (size_t)OUT_F * IN_F;

    prep_kernel<<<8192 + 2048, 256, 0, stream>>>(x, mu, sg, xb, kh, mh);

    dim3 grid(NROWS / BM * (OUT_F / BN));  // 32 * 16 = 512 blocks
    gemm_fused_kernel<<<grid, 256, 0, stream>>>(xb, kh, mh, gate, out0, out1, out2);
}